// Round 3
// baseline (89.805 us; speedup 1.0000x reference)
//
#include <hip/hip_runtime.h>

#define MARGIN 1.0f
#define BATCH 256
#define N 512
#define THREADS 256
#define JCHUNK 64
#define CHUNKS (N / JCHUNK)          // 8 j-chunks per row
#define NBLOCKS (BATCH * CHUNKS)     // 2048 blocks -> 8 blocks/CU

typedef unsigned long long ull;

// Fixed-point scale for the global sum: 2^20. Per-block rounding error
// <= 0.5*2^-20; over 2048 blocks <= ~1e-3 absolute on a ~1.7e7 total.
#define FIXED_SCALE 1048576.0f

struct Accum {
    ull sum_fixed;      // sum of per-block hinge sums, 2^-20 fixed point
    ull pairs;          // sum of rel*nonrel pair counts (exact integer)
    unsigned int done;  // finished-block counter
};

// Single fused kernel. Block (row, chunk):
//   partial = sum_{i in row, j in chunk} [i rel][j nonrel] relu(MARGIN - (s_i - s_j))
// via branch-free sentinels (t[j] = s_j if nonrel else -1e30; m_i = 1-s_i if
// rel else -1e30; cell = max(m_i + t[j], 0)). Partials land in d_ws via
// INTEGER atomics (order-independent -> deterministic). Last block divides.
__global__ __launch_bounds__(THREADS) void hinge_fused(
    const float* __restrict__ scores,
    const int* __restrict__ rel,
    float* __restrict__ out,
    Accum* __restrict__ ws)
{
    __shared__ float t[JCHUNK];
    __shared__ float wa[THREADS / 64];
    __shared__ int   wr[THREADS / 64];
    __shared__ int   nnr_sh;

    const int bid = blockIdx.x;
    const int row = bid >> 3;                // bid / CHUNKS
    const int chunk = bid & (CHUNKS - 1);
    const int tid = threadIdx.x;

    const float* srow = scores + row * N;
    const int*  rrow = rel + row * N;

    // Wave 0 stages this block's j-chunk with sentinels and counts nonrel.
    if (tid < JCHUNK) {
        const int j = chunk * JCHUNK + tid;
        const int nonrel = (rrow[j] == 0);
        t[tid] = nonrel ? srow[j] : -1e30f;
        const ull m = __ballot(nonrel);      // wave 0 only: lanes 0..63 = chunk
        if (tid == 0) nnr_sh = __popcll(m);
    }

    // Each thread owns two candidate-i items (coalesced).
    const float s0 = srow[tid];
    const float s1 = srow[tid + THREADS];
    const int r0 = rrow[tid] > 0;
    const int r1 = rrow[tid + THREADS] > 0;
    const float m0 = r0 ? (MARGIN - s0) : -1e30f;
    const float m1 = r1 ? (MARGIN - s1) : -1e30f;

    __syncthreads();

    float acc0 = 0.f, acc1 = 0.f;
    const float4* tq = (const float4*)t;     // uniform addr -> ds_read_b128 broadcast
    #pragma unroll
    for (int q = 0; q < JCHUNK / 4; ++q) {
        const float4 v = tq[q];
        float x, y;
        x = m0 + v.x; y = m1 + v.x; acc0 += fmaxf(x, 0.f); acc1 += fmaxf(y, 0.f);
        x = m0 + v.y; y = m1 + v.y; acc0 += fmaxf(x, 0.f); acc1 += fmaxf(y, 0.f);
        x = m0 + v.z; y = m1 + v.z; acc0 += fmaxf(x, 0.f); acc1 += fmaxf(y, 0.f);
        x = m0 + v.w; y = m1 + v.w; acc0 += fmaxf(x, 0.f); acc1 += fmaxf(y, 0.f);
    }

    // Fixed-order block reduction (deterministic within the block).
    float a = acc0 + acc1;
    int   c = r0 + r1;
    for (int off = 32; off > 0; off >>= 1) {
        a += __shfl_down(a, off, 64);
        c += __shfl_down(c, off, 64);
    }
    const int wave = tid >> 6;
    const int lane = tid & 63;
    if (lane == 0) { wa[wave] = a; wr[wave] = c; }
    __syncthreads();

    if (tid == 0) {
        const float bsum = wa[0] + wa[1] + wa[2] + wa[3];
        const int   crel = wr[0] + wr[1] + wr[2] + wr[3];   // rel count, full row
        const ull fixed = (ull)llrintf(bsum * FIXED_SCALE);
        atomicAdd(&ws->sum_fixed, fixed);                    // integer: order-free
        atomicAdd(&ws->pairs, (ull)crel * (ull)nnr_sh);
        __threadfence();                                     // device-scope release
        const unsigned int old = atomicAdd(&ws->done, 1u);
        if (old == NBLOCKS - 1) {
            // All blocks' adds precede their counter bump -> totals complete.
            const ull total_fixed = atomicAdd(&ws->sum_fixed, 0ULL);
            const ull pairs      = atomicAdd(&ws->pairs, 0ULL);
            const double total = (double)total_fixed * (1.0 / 1048576.0);
            out[0] = pairs ? (float)(total / (double)pairs) : 0.f;
        }
    }
}

extern "C" void kernel_launch(void* const* d_in, const int* in_sizes, int n_in,
                              void* d_out, int out_size, void* d_ws, size_t ws_size,
                              hipStream_t stream) {
    const float* scores = (const float*)d_in[0];
    const int* rel = (const int*)d_in[1];
    float* out = (float*)d_out;
    Accum* ws = (Accum*)d_ws;

    // d_ws is poisoned 0xAA and never re-poisoned between replays: zero the
    // 24-byte accumulator block every launch (async memset -> graph memset node).
    hipMemsetAsync(ws, 0, sizeof(Accum), stream);
    hinge_fused<<<NBLOCKS, THREADS, 0, stream>>>(scores, rel, out, ws);
}

// Round 4
// 31.993 us; speedup vs baseline: 2.8070x; 2.8070x over previous
//
#include <hip/hip_runtime.h>

#define MARGIN 1.0f
#define BATCH 256
#define N 512
#define THREADS 256
#define JCHUNK 64
#define CHUNKS 8
#define NBLOCKS (BATCH * CHUNKS)     // 2048 blocks -> 8 blocks/CU
#define NGROUP 32                    // distributed accumulator / counter lines
#define GMASK (NGROUP - 1)
#define PER_GROUP (NBLOCKS / NGROUP) // 64 blocks per group

typedef unsigned long long ull;

// Fixed-point scale 2^20: per-block quantization error <= 2^-21 plus float
// rounding of bsum (~2^-24 rel); total abs error over 2048 blocks ~1e-3 on a
// ~1.7e7 sum -> ~1e-10 on the output. Integer adds are order-independent ->
// bit-deterministic across graph replays.
#define FIXED_SCALE 1048576.0f

struct __align__(64) AccLine { ull sum_fixed; ull pairs; ull pad[6]; };      // 64 B
struct __align__(64) CtrLine { unsigned int v; unsigned int pad[15]; };      // 64 B
// ws layout: AccLine acc[32] (2048 B) | CtrLine l1[32] (2048 B) | uint l2 (64 B)

__global__ __launch_bounds__(THREADS) void hinge_fused(
    const float* __restrict__ scores,
    const int* __restrict__ rel,
    float* __restrict__ out,
    AccLine* __restrict__ acc,
    CtrLine* __restrict__ l1,
    unsigned int* __restrict__ l2)
{
    __shared__ float t[JCHUNK];
    __shared__ float wa[THREADS / 64];
    __shared__ int   wr[THREADS / 64];
    __shared__ int   nnr_sh;

    const int bid = blockIdx.x;
    const int row = bid >> 3;                // bid / CHUNKS
    const int chunk = bid & (CHUNKS - 1);
    const int tid = threadIdx.x;

    const float* srow = scores + row * N;
    const int*  rrow = rel + row * N;

    // Wave 0 stages this block's j-chunk with sentinels and counts nonrel.
    if (tid < JCHUNK) {
        const int j = chunk * JCHUNK + tid;
        const int nonrel = (rrow[j] == 0);
        t[tid] = nonrel ? srow[j] : -1e30f;
        const ull m = __ballot(nonrel);      // wave 0 fully active here
        if (tid == 0) nnr_sh = __popcll(m);
    }

    // Each thread owns two candidate-i items (coalesced).
    const float s0 = srow[tid];
    const float s1 = srow[tid + THREADS];
    const int r0 = rrow[tid] > 0;
    const int r1 = rrow[tid + THREADS] > 0;
    const float m0 = r0 ? (MARGIN - s0) : -1e30f;
    const float m1 = r1 ? (MARGIN - s1) : -1e30f;

    __syncthreads();

    float acc0 = 0.f, acc1 = 0.f;
    const float4* tq = (const float4*)t;     // uniform addr -> ds_read_b128 broadcast
    #pragma unroll
    for (int q = 0; q < JCHUNK / 4; ++q) {
        const float4 v = tq[q];
        float x, y;
        x = m0 + v.x; y = m1 + v.x; acc0 += fmaxf(x, 0.f); acc1 += fmaxf(y, 0.f);
        x = m0 + v.y; y = m1 + v.y; acc0 += fmaxf(x, 0.f); acc1 += fmaxf(y, 0.f);
        x = m0 + v.z; y = m1 + v.z; acc0 += fmaxf(x, 0.f); acc1 += fmaxf(y, 0.f);
        x = m0 + v.w; y = m1 + v.w; acc0 += fmaxf(x, 0.f); acc1 += fmaxf(y, 0.f);
    }

    // Fixed-order block reduction (deterministic within the block).
    float a = acc0 + acc1;
    int   c = r0 + r1;
    for (int off = 32; off > 0; off >>= 1) {
        a += __shfl_down(a, off, 64);
        c += __shfl_down(c, off, 64);
    }
    const int wave = tid >> 6;
    const int lane = tid & 63;
    if (lane == 0) { wa[wave] = a; wr[wave] = c; }
    __syncthreads();

    if (tid == 0) {
        const float bsum = wa[0] + wa[1] + wa[2] + wa[3];
        const int   crel = wr[0] + wr[1] + wr[2] + wr[3];   // rel count, full row
        const ull fixed = (ull)llrintf(bsum * FIXED_SCALE);
        const int g = bid & GMASK;                           // spread consecutive bids

        // Distributed partial accumulation: relaxed agent-scope RMWs, 32 lines.
        __hip_atomic_fetch_add(&acc[g].sum_fixed, fixed,
                               __ATOMIC_RELAXED, __HIP_MEMORY_SCOPE_AGENT);
        __hip_atomic_fetch_add(&acc[g].pairs, (ull)crel * (ull)nnr_sh,
                               __ATOMIC_RELAXED, __HIP_MEMORY_SCOPE_AGENT);

        // Level-1 done counter (own cacheline per group), RELEASE orders the
        // RMWs above before the count becomes visible.
        const unsigned int o1 = __hip_atomic_fetch_add(&l1[g].v, 1u,
                               __ATOMIC_RELEASE, __HIP_MEMORY_SCOPE_AGENT);
        if (o1 == PER_GROUP - 1) {
            __threadfence();                                 // acquire side (closer only)
            const unsigned int o2 = __hip_atomic_fetch_add(l2, 1u,
                                   __ATOMIC_ACQ_REL, __HIP_MEMORY_SCOPE_AGENT);
            if (o2 == NGROUP - 1) {
                __threadfence();                             // final acquire
                ull total_fixed = 0, pairs = 0;
                #pragma unroll
                for (int k = 0; k < NGROUP; ++k) {
                    total_fixed += __hip_atomic_load(&acc[k].sum_fixed,
                                   __ATOMIC_RELAXED, __HIP_MEMORY_SCOPE_AGENT);
                    pairs       += __hip_atomic_load(&acc[k].pairs,
                                   __ATOMIC_RELAXED, __HIP_MEMORY_SCOPE_AGENT);
                }
                const double total = (double)total_fixed * (1.0 / 1048576.0);
                out[0] = pairs ? (float)(total / (double)pairs) : 0.f;
            }
        }
    }
}

extern "C" void kernel_launch(void* const* d_in, const int* in_sizes, int n_in,
                              void* d_out, int out_size, void* d_ws, size_t ws_size,
                              hipStream_t stream) {
    const float* scores = (const float*)d_in[0];
    const int* rel = (const int*)d_in[1];
    float* out = (float*)d_out;

    AccLine* acc = (AccLine*)d_ws;
    CtrLine* l1  = (CtrLine*)((char*)d_ws + sizeof(AccLine) * NGROUP);
    unsigned int* l2 = (unsigned int*)((char*)d_ws + sizeof(AccLine) * NGROUP
                                                   + sizeof(CtrLine) * NGROUP);

    // Zero the 4160-byte combining tree every launch (d_ws is poisoned 0xAA
    // once and never re-poisoned between replays).
    hipMemsetAsync(d_ws, 0, sizeof(AccLine) * NGROUP + sizeof(CtrLine) * NGROUP + 64,
                   stream);
    hinge_fused<<<NBLOCKS, THREADS, 0, stream>>>(scores, rel, out, acc, l1, l2);
}